// Round 8
// baseline (166.779 us; speedup 1.0000x reference)
//
#include <hip/hip_runtime.h>
#include <hip/hip_bf16.h>

#define NROWS 4096
#define DDIM  256
#define EPS   1e-8f
// Normalized rows are scaled by sqrt(2*log2(e)) so the MFMA dot product IS the
// exp2 argument: exp2(<se_i, se_j>) = exp(<e_i,e_j>/T), T = 0.5.
#define SCALE 1.69864944f
#define LN2   0.69314718056f

#define NJ 32          // j-slices (grid.y)
#define JS 256         // cols per slice -> 16 groups of 16 cols

typedef __attribute__((ext_vector_type(8))) short short8;
typedef __attribute__((ext_vector_type(4))) float f32x4;

#if __has_builtin(__builtin_amdgcn_exp2f)
#define EXP2F(x) __builtin_amdgcn_exp2f(x)
#else
#define EXP2F(x) exp2f(x)
#endif

__device__ __forceinline__ unsigned short f2bf(float x) {
    union { __hip_bfloat16 h; unsigned short u; } c;
    c.h = __float2bfloat16(x);
    return c.u;
}
__device__ __forceinline__ float bf2f(unsigned short u) {
    union { unsigned int i; float f; } c;
    c.i = ((unsigned int)u) << 16;
    return c.f;
}

// ---------------------------------------------------------------------------
// Kernel 1: row L2-normalize fp32 -> scaled bf16, written in BOTH row-major
// (for loss_kernel) and MFMA-fragment order gfrag (for simsum, so all simsum
// global reads are lane-contiguous). Zeros S / cell / counter.
// One wave per row: grid = 2N/4 blocks x 256 threads.
// Fragment address of (row r, elem k):
//   (r>>4)*4096 + (k>>5)*512 + (((k&31)>>3)*16 + (r&15))*8 + (k&7)
// Lane L holds k = 4L..4L+3 -> ks=L>>3, quad=(L>>1)&3, e=(L&1)*4 (ushort4).
__global__ void normalize_kernel(const float* __restrict__ a,
                                 const float* __restrict__ b,
                                 unsigned short* __restrict__ en,
                                 unsigned short* __restrict__ gfrag,
                                 float* __restrict__ S,
                                 float* __restrict__ cell,
                                 unsigned int* __restrict__ counter, int N) {
    const int wave = threadIdx.x >> 6, lane = threadIdx.x & 63;
    const int row = blockIdx.x * 4 + wave;
    const float* src = (row < N) ? (a + (size_t)row * DDIM)
                                 : (b + (size_t)(row - N) * DDIM);
    const float4 v = reinterpret_cast<const float4*>(src)[lane];
    float ss = v.x * v.x + v.y * v.y + v.z * v.z + v.w * v.w;
    #pragma unroll
    for (int off = 32; off > 0; off >>= 1) ss += __shfl_xor(ss, off);
    const float inv = SCALE / fmaxf(sqrtf(ss), EPS * SCALE);
    ushort4 o;
    o.x = f2bf(v.x * inv);
    o.y = f2bf(v.y * inv);
    o.z = f2bf(v.z * inv);
    o.w = f2bf(v.w * inv);
    *reinterpret_cast<ushort4*>(en + (size_t)row * DDIM + lane * 4) = o;
    const int ks = lane >> 3, quad = (lane >> 1) & 3, e = (lane & 1) * 4;
    const size_t fo = (size_t)(row >> 4) * 4096 + ks * 512
                      + (quad * 16 + (row & 15)) * 8 + e;
    *reinterpret_cast<ushort4*>(gfrag + fo) = o;
    if (lane == 0 && row < N) S[row] = 0.0f;
    if (blockIdx.x == 0 && threadIdx.x == 0) { *cell = 0.0f; *counter = 0u; }
}

// ---------------------------------------------------------------------------
// Kernel 2: UNMASKED exp2 row-sums via 16x16x32 bf16 MFMA.
// NO LDS, NO barriers, NO DMA: B fragments are loaded straight to VGPRs from
// fragment-ordered gfrag (lane-contiguous 16B; L2-resident; all 4 waves of a
// block read the identical stream -> L1 reuse). Each wave owns 64 A-rows
// register-resident (afrag[4][8] = 128 VGPRs -> 4 MFMAs per B-frag) and
// sweeps its 256-col j-slice in 16-col groups, register-double-buffering B
// at half-group granularity (load half h+1 while 16 MFMAs consume half h).
// grid = (16 i-blocks of 256 rows, NJ j-slices), block = 256 (4 waves).
// MFMA 16x16x32 bf16 verified layouts:
//   A/B operand: elem j of lane l = M[base + (l&15)][ks*32 + (l>>4)*8 + j]
//   C/D:         reg r of lane l  = C[(l>>4)*4 + r][l&15]
// B-stream address is linear: slot H (= group*2 + half, H=0..31) lives at
//   gfrag + (jb>>4)*4096 + H*2048 + k4*512 + lane*8,  k4 = 0..3.
__global__ __launch_bounds__(256, 2) void simsum_kernel(
        const short* __restrict__ gfrag,
        float* __restrict__ S) {
    const int tid = threadIdx.x;
    const int wave = tid >> 6, lane = tid & 63;
    const int lrow = lane & 15, quad = lane >> 4;
    const int i0 = blockIdx.x * 256 + wave * 64;
    const int jb = blockIdx.y * JS;

    // A fragments: 4 row-tiles (16 rows each) x 8 k-steps = 128 VGPRs.
    short8 afrag[4][8];
    #pragma unroll
    for (int t = 0; t < 4; ++t)
        #pragma unroll
        for (int ks = 0; ks < 8; ++ks)
            afrag[t][ks] = *reinterpret_cast<const short8*>(
                gfrag + (size_t)(blockIdx.x * 16 + wave * 4 + t) * 4096
                      + ks * 512 + lane * 8);

    float rowsum[4][4];
    #pragma unroll
    for (int t = 0; t < 4; ++t)
        #pragma unroll
        for (int r = 0; r < 4; ++r) rowsum[t][r] = 0.0f;

    const short* bptr = gfrag + (size_t)(jb >> 4) * 4096 + lane * 8;
    short8 bf0[4], bf1[4];

    // Prologue: half (g=0, h=0) -> bf0.
    #pragma unroll
    for (int k4 = 0; k4 < 4; ++k4)
        bf0[k4] = *reinterpret_cast<const short8*>(bptr + k4 * 512);

    for (int g = 0; g < 16; ++g) {
        const short* gb = bptr + g * 4096;
        // Load half (g,1) -> bf1 while MFMAing half (g,0) from bf0.
        #pragma unroll
        for (int k4 = 0; k4 < 4; ++k4)
            bf1[k4] = *reinterpret_cast<const short8*>(gb + 2048 + k4 * 512);

        f32x4 acc[4];
        #pragma unroll
        for (int t = 0; t < 4; ++t) acc[t] = f32x4{0.f, 0.f, 0.f, 0.f};
        #pragma unroll
        for (int k4 = 0; k4 < 4; ++k4)
            #pragma unroll
            for (int t = 0; t < 4; ++t)
                acc[t] = __builtin_amdgcn_mfma_f32_16x16x32_bf16(
                    afrag[t][k4], bf0[k4], acc[t], 0, 0, 0);

        // Load half (g+1,0) -> bf0 while MFMAing half (g,1) from bf1.
        if (g + 1 < 16) {
            #pragma unroll
            for (int k4 = 0; k4 < 4; ++k4)
                bf0[k4] = *reinterpret_cast<const short8*>(gb + 4096 + k4 * 512);
        }
        #pragma unroll
        for (int k4 = 0; k4 < 4; ++k4)
            #pragma unroll
            for (int t = 0; t < 4; ++t)
                acc[t] = __builtin_amdgcn_mfma_f32_16x16x32_bf16(
                    afrag[t][4 + k4], bf1[k4], acc[t], 0, 0, 0);

        // Mask-free epilogue: 16 exp2 + 16 adds (diagonals fixed in loss).
        #pragma unroll
        for (int t = 0; t < 4; ++t)
            #pragma unroll
            for (int r = 0; r < 4; ++r)
                rowsum[t][r] += EXP2F(acc[t][r]);
    }

    // Reduce each rowsum over the 16 lanes sharing a quad, then one atomic.
    #pragma unroll
    for (int t = 0; t < 4; ++t) {
        #pragma unroll
        for (int r = 0; r < 4; ++r) {
            float v = rowsum[t][r];
            v += __shfl_xor(v, 1);
            v += __shfl_xor(v, 2);
            v += __shfl_xor(v, 4);
            v += __shfl_xor(v, 8);
            rowsum[t][r] = v;
        }
        if (lrow < 4) {
            const float v = (lrow == 0) ? rowsum[t][0]
                          : (lrow == 1) ? rowsum[t][1]
                          : (lrow == 2) ? rowsum[t][2]
                          :               rowsum[t][3];
            atomicAdd(&S[i0 + t * 16 + quad * 4 + lrow], v);
        }
    }
}

// ---------------------------------------------------------------------------
// Kernel 3: per-row diagonal corrections + final loss.
// grid = 64 blocks x 256 threads; wave gw handles rows gw*16..gw*16+15.
// selfdot/posdot recomputed in fp32 from the same scaled-bf16 data.
//   contrib_i = posdot*ln2 - ln(S_i - exp2(selfdot) - exp2(posdot))
// Last block (device-scope counter) writes the mean.
__global__ void loss_kernel(const unsigned short* __restrict__ en,
                            const float* __restrict__ S,
                            float* __restrict__ cell,
                            unsigned int* __restrict__ counter,
                            float* __restrict__ out, int N) {
    const int tid = threadIdx.x;
    const int wave = tid >> 6, lane = tid & 63;
    const int gw = blockIdx.x * 4 + wave;          // 0..255
    float wacc = 0.0f;
    for (int rr = 0; rr < 16; ++rr) {
        const int row = gw * 16 + rr;
        const ushort4 ua = *reinterpret_cast<const ushort4*>(
            en + (size_t)row * DDIM + lane * 4);
        const ushort4 ub = *reinterpret_cast<const ushort4*>(
            en + (size_t)(N + row) * DDIM + lane * 4);
        const float a0 = bf2f(ua.x), a1 = bf2f(ua.y),
                    a2 = bf2f(ua.z), a3 = bf2f(ua.w);
        const float b0 = bf2f(ub.x), b1 = bf2f(ub.y),
                    b2 = bf2f(ub.z), b3 = bf2f(ub.w);
        float sd = a0 * a0 + a1 * a1 + a2 * a2 + a3 * a3;
        float pd = a0 * b0 + a1 * b1 + a2 * b2 + a3 * b3;
        #pragma unroll
        for (int off = 32; off > 0; off >>= 1) {
            sd += __shfl_xor(sd, off);
            pd += __shfl_xor(pd, off);
        }
        if (lane == 0) {
            const float Sc = S[row] - EXP2F(sd) - EXP2F(pd);
            wacc += pd * LN2 - LN2 * __log2f(Sc);
        }
    }
    __shared__ float bs[4];
    if (lane == 0) bs[wave] = wacc;
    __syncthreads();
    if (tid == 0) {
        atomicAdd(cell, bs[0] + bs[1] + bs[2] + bs[3]);
        __threadfence();
        const unsigned int old = atomicAdd(counter, 1u);
        if (old == gridDim.x - 1) {
            const float tot = atomicAdd(cell, 0.0f);   // device-scope read
            out[0] = -tot / (float)N;
        }
    }
}

// ---------------------------------------------------------------------------
extern "C" void kernel_launch(void* const* d_in, const int* in_sizes, int n_in,
                              void* d_out, int out_size, void* d_ws, size_t ws_size,
                              hipStream_t stream) {
    const float* a = (const float*)d_in[0];
    const float* b = (const float*)d_in[1];
    float* out = (float*)d_out;
    const int N = NROWS;

    char* ws = (char*)d_ws;
    unsigned short* en = (unsigned short*)ws;                   // 4 MB
    unsigned short* gfrag = en + (size_t)2 * N * DDIM;          // 4 MB
    float* S = (float*)(gfrag + (size_t)2 * N * DDIM);
    float* cell = S + N;
    unsigned int* counter = (unsigned int*)(cell + 1);

    normalize_kernel<<<(2 * N) / 4, 256, 0, stream>>>(a, b, en, gfrag, S,
                                                      cell, counter, N);
    simsum_kernel<<<dim3(N / 256, NJ), 256, 0, stream>>>((const short*)gfrag, S);
    loss_kernel<<<64, 256, 0, stream>>>(en, S, cell, counter, out, N);
}